// Round 13
// baseline (241.503 us; speedup 1.0000x reference)
//
#include <hip/hip_runtime.h>

// Problem constants
#define HW    224
#define IMG   (HW * HW)     // 50176 px per image
#define IMG4  (IMG / 4)     // 12544 float4 per image
#define TILES 49            // 7x7 tiles of 32x32 px per image

// ROUND 12 = MEASUREMENT ROUND. Identical round-11 kernel, launched TWICE
// (idempotent). dur_1x = C + T = 208.8 (round 11); dur_2x = C + ~2T.
// => T (true kernel time) = dur_2x - 208.8, C = harness overhead in the
// timed graph. Distinguishes "kernel ~80us (store path 3x worse than fill)"
// from "kernel ~30-40us, overhead-dominated" — the top-5 counter table
// can't show our kernel (all slots are 122-128us fills), so this A/B is
// the only way to see T.

__global__ __launch_bounds__(256) void gaze_cone_kernel(
    const float* __restrict__ xy,          // [B,2] gaze direction
    const float* __restrict__ head_point,  // [B,2] pixel coords
    float* __restrict__ out)               // [B,1,224,224]
{
#pragma clang fp contract(off)
    const float SCALE = 3.81971863420548805845f;  // 12/pi
    const float CPHI  = 0.965474f;                // cos(15.1 deg)
    const float SPHI  = 0.260505f;                // sin(15.1 deg)

    const int bid = blockIdx.x;
    const int b   = bid / TILES;           // image
    const int t   = bid - b * TILES;       // tile 0..48
    const int tx  = t % 7;
    const int ty  = t / 7;

    const int tid = threadIdx.x;
    const int w   = tid >> 6;              // wave 0..3 (8 rows each)
    const int l   = tid & 63;

    const int row = ty * 32 + w * 8 + (l >> 3);   // global row i
    const int c4  = tx * 8 + (l & 7);             // global float4-col (0..55)
    const int k0  = c4 << 2;                      // global px col

    const float x0 = xy[2 * b];
    const float x1 = xy[2 * b + 1];
    const float h0 = head_point[2 * b];
    const float h1 = head_point[2 * b + 1];

    // ---- wave-level SAT: 15.1deg cone from (h0,h1) vs this wave's 32x8 tile
    const float upx = x0 * CPHI - x1 * SPHI;   // u+
    const float upy = x0 * SPHI + x1 * CPHI;
    const float umx = x0 * CPHI + x1 * SPHI;   // u-
    const float umy = x1 * CPHI - x0 * SPHI;

    const float bx0 = (float)(tx * 32 - 1);
    const float bx1 = (float)(tx * 32 + 32);
    const float by0 = (float)(ty * 32 + w * 8 - 1);
    const float by1 = (float)(ty * 32 + w * 8 + 8);

    const float n1x = -umy, n1y = umx;
    const float n2x = upy,  n2y = -upx;

    const float md1 = fmaxf(n1x * bx0, n1x * bx1) + fmaxf(n1y * by0, n1y * by1)
                    - (n1x * h0 + n1y * h1);
    const float md2 = fmaxf(n2x * bx0, n2x * bx1) + fmaxf(n2y * by0, n2y * by1)
                    - (n2x * h0 + n2y * h1);

    bool sep = (md1 < 0.0f) || (md2 < 0.0f);
    sep = sep || (umx >= 0.0f && upx >= 0.0f && bx1 < h0);
    sep = sep || (umx <= 0.0f && upx <= 0.0f && bx0 > h0);
    sep = sep || (umy >= 0.0f && upy >= 0.0f && by1 < h1);
    sep = sep || (umy <= 0.0f && upy <= 0.0f && by0 > h1);

    float4 r;
    if (sep) {
        r = make_float4(0.0f, 0.0f, 0.0f, 0.0f);
    } else {
        // ---- exact round-9/11 math, bit-identical op order ----
        const float xyn = sqrtf(x0 * x0 + x1 * x1);
        const float dy   = (float)row - h1;
        const float dy2  = dy * dy;
        const float dyx1 = dy * x1;

        float* rp = &r.x;
#pragma unroll
        for (int j = 0; j < 4; ++j) {
            float dx    = (float)(k0 + j) - h0;
            float num   = dx * x0 + dyx1;          // mul, add (contract off)
            float d2    = dx * dx + dy2;
            float an    = sqrtf(d2);               // IEEE sqrt
            float denom = an * xyn;
            float dsel  = (denom > 0.0f) ? denom : 1.0f;
            float c     = num / dsel;              // IEEE div
            float u     = 1.0f - c;                // exact (Sterbenz)
            float s     = __builtin_amdgcn_sqrtf(u + u);
            float poly  = fmaf(u, fmaf(u, 0.01875f, 0.08333333333333333f), 1.0f);
            float theta = s * poly;
            float m     = fmaf(theta, -SCALE, 1.0f);
            rp[j] = fmaxf(m, 0.0f);                // NaN/neg -> +0.0f
        }
    }

    reinterpret_cast<float4*>(out)[(size_t)b * IMG4 + row * 56 + c4] = r;
}

extern "C" void kernel_launch(void* const* d_in, const int* in_sizes, int n_in,
                              void* d_out, int out_size, void* d_ws, size_t ws_size,
                              hipStream_t stream) {
    const float* xy = (const float*)d_in[0];
    const float* hp = (const float*)d_in[1];
    float* out      = (float*)d_out;

    const int B = in_sizes[0] / 2;   // 1024

    // MEASUREMENT: launch twice (idempotent, identical output each time).
    // dur_2x - 208.8 isolates the true kernel time T.
    gaze_cone_kernel<<<B * TILES, 256, 0, stream>>>(xy, hp, out);
    gaze_cone_kernel<<<B * TILES, 256, 0, stream>>>(xy, hp, out);
}